// Round 2
// baseline (396.390 us; speedup 1.0000x reference)
//
#include <hip/hip_runtime.h>
#include <hip/hip_bf16.h>

// Problem constants (from reference): B,Q,C,P,A = 32,300,81,300,29
#define BB 32
#define QQ 300
#define CC 81
#define PP 300
#define AA 29

// Flat output layout (fp32 elements), concatenated in reference return order:
// scores(B,Q) | labels(B,Q) | boxes(B,Q,4) | score(B,A,Q,Q+1) | h_mask(B,Q) | o_mask(B,Q+1)
constexpr long long OFF_SCORES = 0;
constexpr long long OFF_LABELS = OFF_SCORES + (long long)BB * QQ;            // 9600
constexpr long long OFF_BOXES  = OFF_LABELS + (long long)BB * QQ;            // 19200
constexpr long long OFF_SCORE  = OFF_BOXES  + (long long)BB * QQ * 4;        // 57600
constexpr long long SCORE_ELEMS = (long long)BB * AA * QQ * (QQ + 1);        // 83,798,400
constexpr long long OFF_HMASK  = OFF_SCORE + SCORE_ELEMS;                    // 83,856,000
constexpr long long OFF_OMASK  = OFF_HMASK + (long long)BB * QQ;             // 83,865,600
// total = 83,875,232 elements

// One thread per (b,q): softmax max/argmax, boxes, masks.
__global__ void cls_box_mask_kernel(const float* __restrict__ logits,
                                    const float* __restrict__ boxes_in,
                                    const float* __restrict__ tsize,
                                    float* __restrict__ out) {
    int t = blockIdx.x * blockDim.x + threadIdx.x;
    if (t >= BB * QQ) return;
    int b = t / QQ;
    int q = t - b * QQ;

    const float* l = logits + (long long)t * CC;

    // Pass 1: global max (all 81) + max/argmax over first 80 (first-index tie-break).
    float m = -1e30f;
    float best = -1e30f;
    int am = 0;
    for (int c = 0; c < CC; ++c) {
        float x = l[c];
        m = fmaxf(m, x);
        if (c < CC - 1 && x > best) { best = x; am = c; }
    }
    // Pass 2: softmax denominator (loads hit L1).
    float s = 0.0f;
    for (int c = 0; c < CC; ++c) {
        s += __expf(l[c] - m);
    }
    float score = __expf(best - m) / s;

    out[OFF_SCORES + t] = score;
    out[OFF_LABELS + t] = (float)am;

    // Boxes: cxcywh -> xyxy, scaled by [img_w, img_h, img_w, img_h].
    float cx = boxes_in[4 * (long long)t + 0];
    float cy = boxes_in[4 * (long long)t + 1];
    float w  = boxes_in[4 * (long long)t + 2];
    float h  = boxes_in[4 * (long long)t + 3];
    float img_h = tsize[2 * b + 0];
    float img_w = tsize[2 * b + 1];
    out[OFF_BOXES + 4 * (long long)t + 0] = (cx - 0.5f * w) * img_w;
    out[OFF_BOXES + 4 * (long long)t + 1] = (cy - 0.5f * h) * img_h;
    out[OFF_BOXES + 4 * (long long)t + 2] = (cx + 0.5f * w) * img_w;
    out[OFF_BOXES + 4 * (long long)t + 3] = (cy + 0.5f * h) * img_h;

    // Masks (threshold = 0.0).
    out[OFF_HMASK + t] = (am == 1 && score > 0.0f) ? 1.0f : 0.0f;
    out[OFF_OMASK + (long long)b * (QQ + 1) + q] = (score > 0.0f) ? 1.0f : 0.0f;
    if (q == 0) out[OFF_OMASK + (long long)b * (QQ + 1) + QQ] = 1.0f;
}

// One block per batch b; thread p handles pair p. Scatter sigmoid(actions) into
// out[b, a, h, o'] with o' = (h==o ? Q : o); numpy duplicate semantics: last p wins.
// Auto-detects int64 vs int32 storage of pred_rel_pairs: values are in [0, 300),
// so if stored little-endian int64, every odd 32-bit word is zero.
__global__ void scatter_kernel(const int* __restrict__ pairs,
                               const float* __restrict__ actions,
                               float* __restrict__ out) {
    __shared__ int keys[PP];
    __shared__ int nz;
    int tid = threadIdx.x;
    if (tid == 0) nz = 0;
    __syncthreads();

    int local = 0;
    for (int i = tid; i < BB * PP; i += blockDim.x) local |= pairs[2 * i + 1];
    if (local) atomicOr(&nz, 1);
    __syncthreads();
    bool is64 = (nz == 0);

    int b = blockIdx.x;
    int p = tid;
    int h = -1, o = -1;
    if (p < PP) {
        if (is64) {
            h = pairs[((long long)(b * PP + p)) * 4 + 0];
            o = pairs[((long long)(b * PP + p)) * 4 + 2];
        } else {
            h = pairs[((long long)(b * PP + p)) * 2 + 0];
            o = pairs[((long long)(b * PP + p)) * 2 + 1];
        }
        if (h == o) o = QQ;
        keys[p] = h * (QQ + 1) + o;
    }
    __syncthreads();
    if (p >= PP) return;

    int k = keys[p];
    for (int p2 = p + 1; p2 < PP; ++p2) {
        if (keys[p2] == k) return;  // a later pair writes the same slot: it wins
    }

    const float* act = actions + (long long)(b * PP + p) * AA;
    long long base = OFF_SCORE + (long long)b * AA * QQ * (QQ + 1)
                   + (long long)h * (QQ + 1) + o;
    for (int a = 0; a < AA; ++a) {
        float x = act[a];
        float sg = 1.0f / (1.0f + __expf(-x));
        out[base + (long long)a * QQ * (QQ + 1)] = sg;
    }
}

extern "C" void kernel_launch(void* const* d_in, const int* in_sizes, int n_in,
                              void* d_out, int out_size, void* d_ws, size_t ws_size,
                              hipStream_t stream) {
    const float* logits   = (const float*)d_in[0]; // (B,Q,C)
    const float* boxes_in = (const float*)d_in[1]; // (B,Q,4)
    const float* actions  = (const float*)d_in[2]; // (B,P,A)
    const int*   pairs    = (const int*)d_in[3];   // (B,P,2) int
    const float* tsize    = (const float*)d_in[4]; // (B,2)
    float* out = (float*)d_out;

    // Zero the big scatter target. Async memset is graph-capturable and hits
    // near-peak HBM write BW. (fp32 zero == all-zero bytes)
    hipMemsetAsync((char*)d_out + OFF_SCORE * sizeof(float), 0,
                   (size_t)SCORE_ELEMS * sizeof(float), stream);

    int n = BB * QQ;
    cls_box_mask_kernel<<<(n + 255) / 256, 256, 0, stream>>>(logits, boxes_in, tsize, out);
    scatter_kernel<<<BB, 320, 0, stream>>>(pairs, actions, out);
}